// Round 1
// baseline (25088.124 us; speedup 1.0000x reference)
//
#include <hip/hip_runtime.h>
#include <cmath>

// Problem constants (from reference setup_inputs)
#define NB 128      // batch
#define NT 64       // T
#define ND 768      // D_enc
#define NU 256      // LSTM units
#define NE 256      // embedding dim
#define NV 48       // label vocab
#define NK 1280     // K = E + D + U
#define NK4 320     // NK/4

// ws layout (bytes)
#define WS_WT   0                       // Wt[1024][1280] f32 = 5,242,880
#define WS_XP   5242880                 // Xp[2][320][128][4] f32 = 1,310,720
#define WS_HB   6553600                 // Hbuf[256][128] f32 = 131,072
#define WS_TS   6684672                 // timesteps[128] i32
#define WS_CNT  6685184                 // counters: 4*S u32

__device__ __forceinline__ float sigf(float x) { return 1.0f / (1.0f + expf(-x)); }

// ---------------------------------------------------------------------------
// Build Wt[c][k] = (k<1024 ? W[k][c] : Uw[k-1024][c]), contiguous in k so the
// main kernel's per-column weight reads are wave-uniform scalar loads.
// ---------------------------------------------------------------------------
__global__ void dec_wt(const float* __restrict__ W, const float* __restrict__ Uw,
                       float* __restrict__ Wt) {
  __shared__ float tile[64][65];
  const int kt = blockIdx.x >> 4;   // 20 k-tiles
  const int ct = blockIdx.x & 15;   // 16 c-tiles
  const int k0 = kt * 64, c0 = ct * 64;
  for (int it = 0; it < 16; ++it) {
    int idx = it * 256 + threadIdx.x;
    int kl = idx >> 6, cl = idx & 63;
    int k = k0 + kl;
    float v = (k < 1024) ? W[(size_t)k * 1024 + c0 + cl]
                         : Uw[(size_t)(k - 1024) * 1024 + c0 + cl];
    tile[kl][cl] = v;
  }
  __syncthreads();
  for (int it = 0; it < 16; ++it) {
    int idx = it * 256 + threadIdx.x;
    int cl = idx >> 6, kl = idx & 63;
    Wt[(size_t)(c0 + cl) * NK + k0 + kl] = tile[kl][cl];
  }
}

// ---------------------------------------------------------------------------
// Init: zero counters, timesteps[b] = #nonzero word_ids, build X(step 0):
// targets=BOS=1 -> embed row 1; hai=0 -> inputs[b][0]; h=0.
// Packed X layout: float4 element [k4*128 + b] holds x[b][4k4..4k4+3].
// ---------------------------------------------------------------------------
__global__ void dec_init(const int* __restrict__ word_ids, const float* __restrict__ inputs,
                         const float* __restrict__ embed, float* __restrict__ Xp,
                         int* __restrict__ ts_arr, unsigned int* __restrict__ cnt, int S) {
  const int beta = blockIdx.x, tid = threadIdx.x;
  if (beta == 0) {
    for (int i = tid; i < 4 * S; i += 256) cnt[i] = 0u;
  }
  __shared__ int sc[64];
  if (tid < 64) sc[tid] = (word_ids[beta * 64 + tid] != 0) ? 1 : 0;
  __syncthreads();
  if (tid == 0) {
    int ssum = 0;
    for (int i = 0; i < 64; ++i) ssum += sc[i];
    ts_arr[beta] = ssum;
  }
  float4* xp0 = (float4*)Xp;  // buffer 0
  if (tid < 64) {
    xp0[tid * NB + beta] = ((const float4*)embed)[64 + tid];          // embed[1] (BOS)
    xp0[(256 + tid) * NB + beta] = make_float4(0.f, 0.f, 0.f, 0.f);   // h = 0
  } else if (tid < 256) {
    const int t = tid - 64;
    xp0[(64 + t) * NB + beta] = ((const float4*)inputs)[(size_t)beta * 64 * 192 + t]; // adj=0
  }
}

// ---------------------------------------------------------------------------
// Persistent decoder. 256 blocks x 512 threads.
// Block g: bt = g>>7 (batch half, 64 batches), ut = g&127 (units 2ut,2ut+1).
// Phase 1: z-slice GEMM, 8 waves k-split K=1280, W via uniform s_loads,
//          x via coalesced float4 from packed Xp. LDS reduce.
// Phase 2a: LSTM pointwise for the block's 2 units (c-state in registers),
//          write h into Hbuf and X(s+1) h-part. Arrive counter A[bt].
// Phase 2b: 128 designated blocks (one per batch): wait A, logits+argmax,
//          bookkeeping, write res and X(s+1) emb/hard parts. Arrive B[half].
// Loop top: wait B (X ready). X double-buffered by step parity.
// ---------------------------------------------------------------------------
__global__ __launch_bounds__(512) void dec_main(
    const float* __restrict__ inputs, const float* __restrict__ embed,
    const float* __restrict__ bias, const float* __restrict__ Wo,
    const float* __restrict__ bo, const int* __restrict__ maxlab_p,
    float* __restrict__ out, const float* __restrict__ Wt,
    float* __restrict__ Xp, float* __restrict__ Hbuf,
    const int* __restrict__ ts_arr, unsigned int* __restrict__ cnt, int S) {

  const int g = blockIdx.x;
  const int tid = threadIdx.x;
  const int wave = tid >> 6, lane = tid & 63;
  const int bt = g >> 7, ut = g & 127;
  const int gb = bt * 64 + lane;
  const int kb = __builtin_amdgcn_readfirstlane(wave * 40);  // wave's k4 range

  __shared__ float Zl[8][64][8];
  __shared__ float Zr[64][8];
  __shared__ float hl[256];
  __shared__ float lp[8][48];
  __shared__ float lgs[48];
  __shared__ int ctrl[2];

  float creg = 0.f;  // c-state for threads tid<128 (unit u = tid>>6, lane batch)

  // phase-2b ownership: blocks 0..63 -> even batches, 128..191 -> odd batches
  int p2b = -1;
  if (g < 64) p2b = 2 * g;
  else if (g >= 128 && g < 192) p2b = 2 * (g - 128) + 1;
  int tgt = 1, hai = 0, hreps = 0, tsb = 0, ml = 3;
  if (p2b >= 0 && tid == 0) { tsb = ts_arr[p2b]; ml = maxlab_p[0]; }

  unsigned int* cA = cnt;
  unsigned int* cB = cnt + 2 * S;

  // bias for reduce phase (this thread reduces column index c = wave)
  const int colw = ((wave >> 1) << 8) + 2 * ut + (wave & 1);
  const float bw = bias[colw];
  const int cu = 2 * ut;

  for (int s = 0; s < S; ++s) {
    const float4* xc = (const float4*)Xp + (size_t)(s & 1) * (NK4 * NB);
    float4* xn4 = (float4*)Xp + (size_t)((s + 1) & 1) * (NK4 * NB);
    float* xn = (float*)xn4;

    if (s > 0) {  // wait: X(s) fully written (phase2b of s-1)
      if (tid == 0) {
        while (__hip_atomic_load(&cB[bt * S + (s - 1)], __ATOMIC_RELAXED,
                                 __HIP_MEMORY_SCOPE_AGENT) < 64u)
          __builtin_amdgcn_s_sleep(1);
      }
      __syncthreads();
      __threadfence();  // acquire: invalidate L1 before reading Xp
    }

    // ---- phase 1: partial z for 8 cols, this wave's k-range ----
    float a0 = 0.f, a1 = 0.f, a2 = 0.f, a3 = 0.f, a4 = 0.f, a5 = 0.f, a6 = 0.f, a7 = 0.f;
    for (int i = 0; i < 40; ++i) {
      const int k4 = kb + i;
      const float4 x4 = xc[k4 * NB + gb];
      const float* wp = Wt + (size_t)4 * k4;
#define DOT8(ACC, CC)                                                          \
      {                                                                        \
        const float4 w = *(const float4*)(wp + (size_t)(CC) * NK);             \
        ACC = fmaf(x4.x, w.x, fmaf(x4.y, w.y, fmaf(x4.z, w.z, fmaf(x4.w, w.w, ACC)))); \
      }
      DOT8(a0, cu)        DOT8(a1, cu + 1)
      DOT8(a2, 256 + cu)  DOT8(a3, 257 + cu)
      DOT8(a4, 512 + cu)  DOT8(a5, 513 + cu)
      DOT8(a6, 768 + cu)  DOT8(a7, 769 + cu)
#undef DOT8
    }
    *(float4*)&Zl[wave][lane][0] = make_float4(a0, a1, a2, a3);
    *(float4*)&Zl[wave][lane][4] = make_float4(a4, a5, a6, a7);
    __syncthreads();

    // ---- k-split reduce: thread (c=wave, l=lane) ----
    {
      const int c = wave, l = lane;
      float z = bw;
#pragma unroll
      for (int w2 = 0; w2 < 8; ++w2) z += Zl[w2][l][c];
      Zr[l][c] = z;
    }
    __syncthreads();

    // ---- phase 2a: LSTM pointwise for units 2ut+u, this half's batches ----
    if (tid < 128) {
      const int u = tid >> 6, l = tid & 63;
      const int gbl = bt * 64 + l;
      const float zi = Zr[l][u], zf = Zr[l][2 + u], zg = Zr[l][4 + u], zo = Zr[l][6 + u];
      const float cn = sigf(zf) * creg + sigf(zi) * tanhf(zg);
      const float hv = sigf(zo) * tanhf(cn);
      creg = cn;
      const int ug = 2 * ut + u;
      Hbuf[ug * NB + gbl] = hv;
      xn[(size_t)(((256 + (ug >> 2)) * NB + gbl) * 4 + (ug & 3))] = hv;  // X(s+1) h-part
    }
    __threadfence();
    __syncthreads();
    if (tid == 0) atomicAdd(&cA[bt * S + s], 1u);

    // ---- phase 2b: one block per batch ----
    if (p2b >= 0) {
      const int beta = p2b, bh = beta >> 6;
      if (tid == 0) {
        while (__hip_atomic_load(&cA[bh * S + s], __ATOMIC_RELAXED,
                                 __HIP_MEMORY_SCOPE_AGENT) < 128u)
          __builtin_amdgcn_s_sleep(1);
      }
      __syncthreads();
      __threadfence();

      if (tid < 256) hl[tid] = Hbuf[tid * NB + beta];
      __syncthreads();
      if (tid < 384) {  // logits partials: 48 cols x 8 k-parts
        const int p = tid / 48, v = tid - p * 48;
        float sm = 0.f;
        for (int i = 0; i < 32; ++i) {
          const int u = p * 32 + i;
          sm = fmaf(hl[u], Wo[u * NV + v], sm);
        }
        lp[p][v] = sm;
      }
      __syncthreads();
      if (tid < 48) {
        float sm = bo[tid];
#pragma unroll
        for (int p = 0; p < 8; ++p) sm += lp[p][tid];
        lgs[tid] = sm;
      }
      __syncthreads();
      if (tid == 0) {
        int am = 0;
        float bv = lgs[0];
        for (int v = 1; v < NV; ++v)
          if (lgs[v] > bv) { bv = lgs[v]; am = v; }     // first-max tie-break
        const int preds = (hreps >= ml) ? 2 : am;        // EOW override
        const int res = (hai == tsb) ? 0 : preds;        // BATCH_PAD mask
        out[(size_t)beta * S + s] = (float)res;
        const int inc = (preds == 2 && hai < tsb) ? 1 : 0;
        hai += inc;
        hreps = inc ? 0 : hreps;
        tgt = preds;
        ctrl[0] = tgt;
        ctrl[1] = (hai < tsb) ? hai : hai - 1;           // adj for next step
      }
      __syncthreads();
      const int tg = ctrl[0], adj = ctrl[1];
      if (tid < 64) {
        xn4[tid * NB + beta] = ((const float4*)embed)[tg * 64 + tid];          // emb part
      } else if (tid < 256) {
        const int t = tid - 64;
        xn4[(64 + t) * NB + beta] =
            ((const float4*)inputs)[((size_t)beta * 64 + adj) * 192 + t];      // hard part
      }
      __threadfence();
      __syncthreads();
      if (tid == 0) atomicAdd(&cB[bh * S + s], 1u);
    }
  }
}

// ---------------------------------------------------------------------------
extern "C" void kernel_launch(void* const* d_in, const int* in_sizes, int n_in,
                              void* d_out, int out_size, void* d_ws, size_t ws_size,
                              hipStream_t stream) {
  const float* inputs  = (const float*)d_in[0];
  const int*   wids    = (const int*)d_in[1];
  const float* embed   = (const float*)d_in[2];
  const float* W       = (const float*)d_in[3];
  const float* Uw      = (const float*)d_in[4];
  const float* bias    = (const float*)d_in[5];
  const float* Wo      = (const float*)d_in[6];
  const float* bo      = (const float*)d_in[7];
  const int*   mlab    = (const int*)d_in[8];
  float* out = (float*)d_out;
  const int S = out_size / NB;  // 192

  char* ws = (char*)d_ws;
  float* Wt          = (float*)(ws + WS_WT);
  float* Xp          = (float*)(ws + WS_XP);
  float* Hbuf        = (float*)(ws + WS_HB);
  int* ts            = (int*)(ws + WS_TS);
  unsigned int* cntp = (unsigned int*)(ws + WS_CNT);

  dec_wt<<<320, 256, 0, stream>>>(W, Uw, Wt);
  dec_init<<<128, 256, 0, stream>>>(wids, inputs, embed, Xp, ts, cntp, S);
  dec_main<<<256, 512, 0, stream>>>(inputs, embed, bias, Wo, bo, mlab, out,
                                    Wt, Xp, Hbuf, ts, cntp, S);
}

// Round 2
// 8428.279 us; speedup vs baseline: 2.9767x; 2.9767x over previous
//
#include <hip/hip_runtime.h>
#include <cmath>

typedef unsigned int u32;
typedef unsigned long long u64;

// Problem constants (from reference setup_inputs)
#define NB 128      // batch
#define NT 64       // T
#define ND 768      // D_enc
#define NU 256      // LSTM units
#define NV 48       // label vocab
#define NK 1280     // K = E + D + U

// ws layout (bytes)
#define WS_WT   0                         // Wt[1024][1280] f32 = 5,242,880
#define WS_WOT  5242880                   // Wot[48][256]   f32 = 49,152
#define WS_HG   (WS_WOT + 49152)          // Hg[2][128][256] f32 = 262,144
#define WS_TS   (WS_HG + 262144)          // ts[128] i32
#define WS_CNT  (WS_TS + 512)             // cnt[8*S] u32

__device__ __forceinline__ float sigf(float x) { return 1.0f / (1.0f + expf(-x)); }

union F2U { u64 q; float2 f; };

// ---------------------------------------------------------------------------
// Wt[c][k] = (k<1024 ? W[k][c] : Uw[k-1024][c]) — k-contiguous weight rows.
// ---------------------------------------------------------------------------
__global__ void dec_wt(const float* __restrict__ W, const float* __restrict__ Uw,
                       float* __restrict__ Wt) {
  __shared__ float tile[64][65];
  const int kt = blockIdx.x >> 4;   // 20 k-tiles
  const int ct = blockIdx.x & 15;   // 16 c-tiles
  const int k0 = kt * 64, c0 = ct * 64;
  for (int it = 0; it < 16; ++it) {
    int idx = it * 256 + threadIdx.x;
    int kl = idx >> 6, cl = idx & 63;
    int k = k0 + kl;
    float v = (k < 1024) ? W[(size_t)k * 1024 + c0 + cl]
                         : Uw[(size_t)(k - 1024) * 1024 + c0 + cl];
    tile[kl][cl] = v;
  }
  __syncthreads();
  for (int it = 0; it < 16; ++it) {
    int idx = it * 256 + threadIdx.x;
    int cl = idx >> 6, kl = idx & 63;
    Wt[(size_t)(c0 + cl) * NK + k0 + kl] = tile[kl][cl];
  }
}

// ---------------------------------------------------------------------------
// Init: zero flags, per-batch timestep count, Wot[v][u] = Wo[u][v].
// ---------------------------------------------------------------------------
__global__ void dec_init(const int* __restrict__ wids, const float* __restrict__ Wo,
                         int* __restrict__ ts, u32* __restrict__ cnt,
                         float* __restrict__ Wot, int S) {
  const int t = threadIdx.x;
  for (int i = t; i < 8 * S; i += 256) cnt[i] = 0u;
  if (t < 128) {
    int c = 0;
    for (int i = 0; i < NT; ++i) c += (wids[t * NT + i] != 0) ? 1 : 0;
    ts[t] = c;
  }
  for (int i = t; i < NV * NU; i += 256) {
    int v = i >> 8, u = i & 255;
    Wot[i] = Wo[u * NV + v];
  }
}

// ---------------------------------------------------------------------------
// Persistent decoder: 256 blocks x 512 threads, 1 block/CU.
// Block g: bq=g>>5 (16 batches), ug=g&31 (8 units = 32 gate cols).
// Per step: z-slice GEMM (x from LDS, W from L2-cached global) -> LDS k-split
// reduce -> LSTM pointwise (c in regs) -> h to Hg via sc0sc1 stores ->
// flag+spin (group-local, fan-in 32, NO cache-wide fences) -> read group h
// (sc0sc1) -> redundant per-block logits/argmax/bookkeeping -> rebuild x in
// LDS. Only h + one flag cross blocks; Wt stays L2-resident all 192 steps.
// ---------------------------------------------------------------------------
__global__ __launch_bounds__(512) void dec_main(
    const float* __restrict__ inputs, const float* __restrict__ embed,
    const float* __restrict__ bias, const float* __restrict__ bo,
    const int* __restrict__ mlab, float* __restrict__ out,
    const float* __restrict__ Wt, const float* __restrict__ Wot,
    float* __restrict__ Hg, const int* __restrict__ ts_arr,
    u32* __restrict__ cnt, int S) {

  const int tid = threadIdx.x;
  const int wave = tid >> 6, lane = tid & 63;
  const int g = blockIdx.x;
  const int bq = g >> 5;          // batch group [0,8)
  const int ug = g & 31;          // unit group [0,32)
  const int b_l = lane & 15, cq = lane >> 4;
  const int cu = ug * 8 + 2 * cq; // this lane's base gate column (2 units)

  __shared__ float xL[16][1284];          // x for 16 batches (+4 pad)
  __shared__ float Zl[8][64][13];         // per-wave partial z (pad 13: no conflicts)
  __shared__ float Zr[64][13];            // reduced z
  __shared__ float lgp[16][8][4][6];      // logits k-partials
  __shared__ float lg[16][48];            // logits
  __shared__ int tgtL[16], adjL[16];

  const float4* Wt4  = (const float4*)Wt;
  const float4* Wot4 = (const float4*)Wot;
  const float4* e4   = (const float4*)embed;
  const float4* in4  = (const float4*)inputs;
  u32* Hg32 = (u32*)Hg;
  u64* Hg64 = (u64*)Hg;

  // per-batch bookkeeping state (threads 0..15; identical across group blocks)
  int tgt = 1, hai = 0, hreps = 0, tsb = 0, ml = 3;
  if (tid < 16) { tsb = ts_arr[bq * 16 + tid]; ml = mlab[0]; }
  float cst = 0.f;  // c-state: threads 0..127 own (b=tid&15, u=ug*8+(tid>>4))

  // reduce-phase constants: thread (rl, rs) reduces column col(rl,rs)
  const int rl = tid & 63, rs = tid >> 6;
  const float bw = bias[(rs >> 1) * 256 + ug * 8 + 2 * (rl >> 4) + (rs & 1)];

  // logits mapping: (batch lb, v-group lvg of 6, k-part lks of 64 units)
  const int lb = tid >> 5, lvg = (tid >> 2) & 7, lks = tid & 3;

  // ---- preamble: x_0 = [embed[BOS=1], inputs[b][0], h=0] ----
  {
    const int b = tid >> 5, j = tid & 31;
#pragma unroll
    for (int i = 0; i < 2; ++i) { int c4 = j + 32 * i; *(float4*)&xL[b][4 * c4] = e4[64 + c4]; }
#pragma unroll
    for (int i = 0; i < 6; ++i) { int c4 = j + 32 * i;
      *(float4*)&xL[b][4 * (64 + c4)] = in4[(size_t)(bq * 16 + b) * NT * 192 + c4]; }
#pragma unroll
    for (int i = 0; i < 8; ++i) { int idx = i * 512 + tid; xL[idx >> 8][1024 + (idx & 255)] = 0.f; }
  }
  __syncthreads();

  for (int s = 0; s < S; ++s) {
    // ---- phase 1: partial z, this wave's k-slice (k4 in [wave*40, +40)) ----
    float a0 = 0.f, a1 = 0.f, a2 = 0.f, a3 = 0.f, a4 = 0.f, a5 = 0.f, a6 = 0.f, a7 = 0.f;
    const int kb = wave * 40;
#pragma unroll 2
    for (int i = 0; i < 40; ++i) {
      const int k4 = kb + i;
      const float4 x4 = *(const float4*)&xL[b_l][4 * k4];
#define DOT8(ACC, CC)                                                          \
      {                                                                        \
        const float4 w = Wt4[(size_t)(CC) * 320 + k4];                         \
        ACC = fmaf(x4.x, w.x, fmaf(x4.y, w.y, fmaf(x4.z, w.z, fmaf(x4.w, w.w, ACC)))); \
      }
      DOT8(a0, cu)        DOT8(a1, cu + 1)
      DOT8(a2, 256 + cu)  DOT8(a3, 257 + cu)
      DOT8(a4, 512 + cu)  DOT8(a5, 513 + cu)
      DOT8(a6, 768 + cu)  DOT8(a7, 769 + cu)
#undef DOT8
    }
    {
      float* zp = &Zl[wave][lane][0];
      zp[0] = a0; zp[1] = a1; zp[2] = a2; zp[3] = a3;
      zp[4] = a4; zp[5] = a5; zp[6] = a6; zp[7] = a7;
    }
    __syncthreads();

    // ---- k-split reduce ----
    {
      float z = bw;
#pragma unroll
      for (int w = 0; w < 8; ++w) z += Zl[w][rl][rs];
      Zr[rl][rs] = z;
    }
    __syncthreads();

    const int par = (s + 1) & 1;

    // ---- LSTM pointwise for own (16 b x 8 u); h -> Hg (coherent stores) ----
    if (tid < 128) {
      const int bb = tid & 15, uu = tid >> 4;
      const int l = (uu >> 1) * 16 + bb, p = uu & 1;
      const float zi = Zr[l][0 + p], zf = Zr[l][2 + p], zg = Zr[l][4 + p], zo = Zr[l][6 + p];
      const float cn = sigf(zf) * cst + sigf(zi) * tanhf(zg);
      const float hv = sigf(zo) * tanhf(cn);
      cst = cn;
      __hip_atomic_store(&Hg32[((size_t)par * NB + bq * 16 + bb) * NU + ug * 8 + uu],
                         __float_as_uint(hv), __ATOMIC_RELAXED, __HIP_MEMORY_SCOPE_AGENT);
    }
    asm volatile("s_waitcnt vmcnt(0)" ::: "memory");
    __syncthreads();
    if (tid == 0) {
      atomicAdd(&cnt[bq * S + s], 1u);
      while (__hip_atomic_load(&cnt[bq * S + s], __ATOMIC_RELAXED,
                               __HIP_MEMORY_SCOPE_AGENT) < 32u)
        __builtin_amdgcn_s_sleep(2);
    }
    __syncthreads();

    // ---- read group h (coherent) -> xL h-part ----
#pragma unroll
    for (int i = 0; i < 4; ++i) {
      const int idx = i * 512 + tid;
      const int bb = idx >> 7, r = idx & 127;
      F2U u;
      u.q = __hip_atomic_load(&Hg64[((size_t)par * NB + bq * 16 + bb) * 128 + r],
                              __ATOMIC_RELAXED, __HIP_MEMORY_SCOPE_AGENT);
      ((float2*)&xL[bb][1024])[r] = u.f;
    }
    __syncthreads();

    // ---- logits partials: thread (lb, lvg, lks), 6 v x 64 u-slice ----
    {
      float p0 = 0.f, p1 = 0.f, p2 = 0.f, p3 = 0.f, p4 = 0.f, p5 = 0.f;
      const int vb = lvg * 6;
#pragma unroll 4
      for (int i = 0; i < 16; ++i) {
        const int u4 = lks * 16 + i;
        const float4 h4 = *(const float4*)&xL[lb][1024 + 4 * u4];
#define LDOT(P, VV)                                                            \
        {                                                                      \
          const float4 w = Wot4[(VV) * 64 + u4];                               \
          P = fmaf(h4.x, w.x, fmaf(h4.y, w.y, fmaf(h4.z, w.z, fmaf(h4.w, w.w, P)))); \
        }
        LDOT(p0, vb)     LDOT(p1, vb + 1) LDOT(p2, vb + 2)
        LDOT(p3, vb + 3) LDOT(p4, vb + 4) LDOT(p5, vb + 5)
#undef LDOT
      }
      float* q = &lgp[lb][lvg][lks][0];
      q[0] = p0; q[1] = p1; q[2] = p2; q[3] = p3; q[4] = p4; q[5] = p5;
    }
    __syncthreads();
    for (int idx = tid; idx < 768; idx += 512) {
      const int b = idx / 48, v = idx - b * 48;
      const int vg = v / 6, j = v - vg * 6;
      float sm = bo[v];
#pragma unroll
      for (int k = 0; k < 4; ++k) sm += lgp[b][vg][k][j];
      lg[b][v] = sm;
    }
    __syncthreads();

    // ---- argmax + bookkeeping (redundant per block; deterministic) ----
    if (tid < 16) {
      int am = 0; float bv = lg[tid][0];
      for (int v = 1; v < NV; ++v) { const float x = lg[tid][v]; if (x > bv) { bv = x; am = v; } }
      const int preds = (hreps >= ml) ? 2 : am;
      const int res = (hai == tsb) ? 0 : preds;
      if (ug == 0) out[(size_t)(bq * 16 + tid) * S + s] = (float)res;
      const int inc = (preds == 2 && hai < tsb) ? 1 : 0;
      hai += inc;
      hreps = inc ? 0 : hreps;
      tgt = preds;
      tgtL[tid] = tgt;
      adjL[tid] = (hai < tsb) ? hai : hai - 1;
    }
    __syncthreads();

    // ---- fill x_{s+1} emb + hard parts (h-part already written) ----
    {
      const int b = tid >> 5, j = tid & 31;
      const int tg = tgtL[b], adj = adjL[b];
#pragma unroll
      for (int i = 0; i < 2; ++i) { int c4 = j + 32 * i; *(float4*)&xL[b][4 * c4] = e4[tg * 64 + c4]; }
#pragma unroll
      for (int i = 0; i < 6; ++i) { int c4 = j + 32 * i;
        *(float4*)&xL[b][4 * (64 + c4)] = in4[((size_t)(bq * 16 + b) * NT + adj) * 192 + c4]; }
    }
    __syncthreads();
  }
}

// ---------------------------------------------------------------------------
extern "C" void kernel_launch(void* const* d_in, const int* in_sizes, int n_in,
                              void* d_out, int out_size, void* d_ws, size_t ws_size,
                              hipStream_t stream) {
  const float* inputs = (const float*)d_in[0];
  const int*   wids   = (const int*)d_in[1];
  const float* embed  = (const float*)d_in[2];
  const float* W      = (const float*)d_in[3];
  const float* Uw     = (const float*)d_in[4];
  const float* bias   = (const float*)d_in[5];
  const float* Wo     = (const float*)d_in[6];
  const float* bo     = (const float*)d_in[7];
  const int*   mlab   = (const int*)d_in[8];
  float* out = (float*)d_out;
  const int S = out_size / NB;  // 192

  char* ws = (char*)d_ws;
  float* Wt  = (float*)(ws + WS_WT);
  float* Wot = (float*)(ws + WS_WOT);
  float* Hg  = (float*)(ws + WS_HG);
  int*   ts  = (int*)(ws + WS_TS);
  u32*   cnt = (u32*)(ws + WS_CNT);

  dec_wt<<<320, 256, 0, stream>>>(W, Uw, Wt);
  dec_init<<<1, 256, 0, stream>>>(wids, Wo, ts, cnt, Wot, S);
  dec_main<<<256, 512, 0, stream>>>(inputs, embed, bias, bo, mlab, out,
                                    Wt, Wot, Hg, ts, cnt, S);
}

// Round 3
// 2207.806 us; speedup vs baseline: 11.3634x; 3.8175x over previous
//
#include <hip/hip_runtime.h>
#include <cmath>

typedef unsigned int u32;

// Problem constants
#define NBATCH 128
#define NT 64
#define ND 768
#define NU 256
#define NV 48

// ws layout (bytes)
#define WS_INPW 0                          // inpW[128*64][1024] f32 = 33,554,432
#define WS_EMBW 33554432                   // embW[48][1024] f32   = 196,608
#define WS_UWS  (WS_EMBW + 196608)         // Uws [64][1024] float4 = 1,048,576
#define WS_WOT  (WS_UWS + 1048576)         // WotG[48][256] f32    = 49,152
// total ~34.85 MB

__device__ __forceinline__ float sigf(float x) { return 1.0f / (1.0f + expf(-x)); }

// ---------------------------------------------------------------------------
// inpW[(b*64+t)][c] = inputs[b][t][:] @ W[256:1024][c]   (M=8192,N=1024,K=768)
// 64x64 tile per 256-thread block, 4x4 micro-tile, K-tiles of 32.
// ---------------------------------------------------------------------------
__global__ __launch_bounds__(256) void prep_inpw(
    const float* __restrict__ inputs, const float* __restrict__ W,
    float* __restrict__ inpW) {
  __shared__ float Af[64][36];   // pad 36: 16B-aligned rows, conflict-free
  __shared__ float Bf[32][68];   // pad 68: 16B-aligned rows
  const int mt = blockIdx.x >> 4, nt = blockIdx.x & 15;
  const int m0 = mt * 64, n0 = nt * 64;
  const int tid = threadIdx.x;
  const int ty = tid >> 4, tx = tid & 15;
  const float4* in4 = (const float4*)inputs;
  const float4* W4 = (const float4*)W;
  float acc[4][4] = {};
  for (int kt = 0; kt < 24; ++kt) {
    __syncthreads();
    {
      int idx = tid;
#pragma unroll
      for (int r = 0; r < 2; ++r, idx += 256) {
        const int row = idx >> 3, k4 = idx & 7;
        const float4 a = in4[(size_t)(m0 + row) * 192 + kt * 8 + k4];
        *(float4*)&Af[row][4 * k4] = a;
      }
    }
    {
      int idx = tid;
#pragma unroll
      for (int r = 0; r < 2; ++r, idx += 256) {
        const int kk = idx >> 4, c4 = idx & 15;
        const float4 bv = W4[(size_t)(256 + kt * 32 + kk) * 256 + (n0 >> 2) + c4];
        *(float4*)&Bf[kk][4 * c4] = bv;
      }
    }
    __syncthreads();
#pragma unroll 4
    for (int kk = 0; kk < 32; ++kk) {
      float av[4], bv[4];
#pragma unroll
      for (int j = 0; j < 4; ++j) av[j] = Af[ty * 4 + j][kk];
#pragma unroll
      for (int j = 0; j < 4; ++j) bv[j] = Bf[kk][tx * 4 + j];
#pragma unroll
      for (int i = 0; i < 4; ++i)
#pragma unroll
        for (int j = 0; j < 4; ++j) acc[i][j] = fmaf(av[i], bv[j], acc[i][j]);
    }
  }
#pragma unroll
  for (int i = 0; i < 4; ++i) {
    const float4 o = make_float4(acc[i][0], acc[i][1], acc[i][2], acc[i][3]);
    ((float4*)inpW)[(((size_t)(m0 + ty * 4 + i)) * 1024 + n0 + tx * 4) >> 2] = o;
  }
}

// ---------------------------------------------------------------------------
// embW[v][c] = bias[c] + embed[v][:] @ W[0:256][c]
// ---------------------------------------------------------------------------
__global__ __launch_bounds__(256) void prep_embw(
    const float* __restrict__ embed, const float* __restrict__ W,
    const float* __restrict__ bias, float* __restrict__ embW) {
  const int v = blockIdx.x, tid = threadIdx.x;
  const float4* W4 = (const float4*)W;
  float4 acc = ((const float4*)bias)[tid];
  for (int e = 0; e < 256; ++e) {
    const float s = embed[v * 256 + e];          // uniform -> scalar load
    const float4 w = W4[(size_t)e * 256 + tid];
    acc.x = fmaf(s, w.x, acc.x); acc.y = fmaf(s, w.y, acc.y);
    acc.z = fmaf(s, w.z, acc.z); acc.w = fmaf(s, w.w, acc.w);
  }
  ((float4*)embW)[v * 256 + tid] = acc;
}

// ---------------------------------------------------------------------------
// Uws element (k4, c) = float4{ Uw[4k4+0][c], .., Uw[4k4+3][c] }  (c-coalesced)
// ---------------------------------------------------------------------------
__global__ __launch_bounds__(256) void prep_uws(
    const float* __restrict__ Uw, float* __restrict__ Uws) {
  const int k4 = blockIdx.x, tid = threadIdx.x;
#pragma unroll
  for (int j = 0; j < 4; ++j) {
    const int cc = tid + 256 * j;
    float4 o;
    o.x = Uw[(size_t)(4 * k4 + 0) * 1024 + cc];
    o.y = Uw[(size_t)(4 * k4 + 1) * 1024 + cc];
    o.z = Uw[(size_t)(4 * k4 + 2) * 1024 + cc];
    o.w = Uw[(size_t)(4 * k4 + 3) * 1024 + cc];
    ((float4*)Uws)[(size_t)k4 * 1024 + cc] = o;
  }
}

// Wot[v][u] = Wo[u][v]
__global__ void prep_wot(const float* __restrict__ Wo, float* __restrict__ WotG) {
  const int tid = threadIdx.x;
  for (int v = 0; v < NV; ++v) WotG[v * 256 + tid] = Wo[tid * NV + v];
}

// ---------------------------------------------------------------------------
// Persistent per-batch decoder: 64 blocks x 1024 threads, 2 batches/block.
// NO cross-block communication. Per step:
//   z[c] = embW[tgt] + inpW[b][adj] + h@Uw   (each lane owns 1 col, both batches)
//   -> pointwise LSTM (c-state in regs) -> logits (Wot in LDS) -> argmax ->
//   bookkeeping -> next step. 4 __syncthreads/step.
// ---------------------------------------------------------------------------
__global__ __launch_bounds__(1024) void dec_main(
    const int* __restrict__ wids, const float* __restrict__ bo,
    const int* __restrict__ mlab, float* __restrict__ out,
    const float* __restrict__ inpW, const float* __restrict__ embW,
    const float* __restrict__ Uws, const float* __restrict__ WotG, int S) {

  const int tid = threadIdx.x;
  const int b0 = blockIdx.x * 2;

  __shared__ float hL[2][256];
  __shared__ float zL[2][1024];
  __shared__ float WotL[NV][260];     // pad 260: <=2-way on logits reads
  __shared__ float lgp[2][NV][9];     // k-partials (pad 9)
  __shared__ float lg[2][NV];
  __shared__ int stL[4];              // tgt0, tgt1, adj0, adj1
  __shared__ int tsL[2];

  // ---- init ----
  if (tid < 512) hL[tid >> 8][tid & 255] = 0.f;
  if (tid == 0) { stL[0] = 1; stL[1] = 1; stL[2] = 0; stL[3] = 0; tsL[0] = 0; tsL[1] = 0; }
  for (int i = tid; i < NV * 256; i += 1024) WotL[i >> 8][i & 255] = WotG[i];
  __syncthreads();
  if (tid < 128) {
    const int b = tid >> 6, t = tid & 63;
    if (wids[(b0 + b) * NT + t] != 0) atomicAdd(&tsL[b], 1);
  }
  float cst = 0.f;   // c-state for threads tid<512: (b=tid>>8, u=tid&255)
  __syncthreads();

  int tsb = 0, ml = 3, hai = 0, hreps = 0;
  if (tid < 2) { tsb = tsL[tid]; ml = mlab[0]; }

  const float4* Uws4 = (const float4*)Uws;
  const int c = tid;   // this lane's gate column

  for (int s = 0; s < S; ++s) {
    // table terms for x@W (issued early, hidden under the k-loop)
    const int t0 = stL[0], t1 = stL[1], a0 = stL[2], a1 = stL[3];
    const float e0 = embW[t0 * 1024 + c];
    const float e1 = embW[t1 * 1024 + c];
    const float q0 = inpW[(size_t)((b0) * 64 + a0) * 1024 + c];
    const float q1 = inpW[(size_t)((b0 + 1) * 64 + a1) * 1024 + c];

    // ---- h @ Uw for both batches: weights loaded ONCE, h broadcast from LDS
    float acc0 = 0.f, acc1 = 0.f;
#pragma unroll 8
    for (int k4 = 0; k4 < 64; ++k4) {
      const float4 wv = Uws4[(size_t)k4 * 1024 + c];
      const float4 h0 = *(const float4*)&hL[0][4 * k4];
      const float4 h1 = *(const float4*)&hL[1][4 * k4];
      acc0 = fmaf(wv.x, h0.x, fmaf(wv.y, h0.y, fmaf(wv.z, h0.z, fmaf(wv.w, h0.w, acc0))));
      acc1 = fmaf(wv.x, h1.x, fmaf(wv.y, h1.y, fmaf(wv.z, h1.z, fmaf(wv.w, h1.w, acc1))));
    }
    zL[0][c] = acc0 + e0 + q0;
    zL[1][c] = acc1 + e1 + q1;
    __syncthreads();

    // ---- LSTM pointwise (keras gate order i,f,g,o) ----
    if (tid < 512) {
      const int b = tid >> 8, u = tid & 255;
      const float zi = zL[b][u], zf = zL[b][256 + u];
      const float zg = zL[b][512 + u], zo = zL[b][768 + u];
      const float cn = sigf(zf) * cst + sigf(zi) * tanhf(zg);
      cst = cn;
      hL[b][u] = sigf(zo) * tanhf(cn);
    }
    __syncthreads();

    // ---- logits partials: (b, v, kp) each 32 k (k = kp + 8i: conflict-free) ----
    {
      const int b = tid >> 9, idx = tid & 511, v = idx >> 3, kp = idx & 7;
      if (v < NV) {
        float sm = 0.f;
#pragma unroll 8
        for (int i = 0; i < 32; ++i) {
          const int k = kp + 8 * i;
          sm = fmaf(hL[b][k], WotL[v][k], sm);
        }
        lgp[b][v][kp] = sm;
      }
    }
    __syncthreads();
    if (tid < 128) {
      const int b = tid >> 6, v = tid & 63;
      if (v < NV) {
        float sm = bo[v];
#pragma unroll
        for (int k = 0; k < 8; ++k) sm += lgp[b][v][k];
        lg[b][v] = sm;
      }
    }
    __syncthreads();

    // ---- argmax (first-max tie-break) + bookkeeping, 1 thread per batch ----
    if (tid < 2) {
      const int b = tid;
      int am = 0;
      float bv = lg[b][0];
      for (int v = 1; v < NV; ++v) {
        const float x = lg[b][v];
        if (x > bv) { bv = x; am = v; }
      }
      const int preds = (hreps >= ml) ? 2 : am;   // matches ref (hreps stays 0)
      const int res = (hai == tsb) ? 0 : preds;
      out[(size_t)(b0 + b) * S + s] = (float)res;
      const int inc = (preds == 2 && hai < tsb) ? 1 : 0;
      hai += inc;
      hreps = inc ? 0 : hreps;
      stL[b] = preds;
      stL[2 + b] = (hai < tsb) ? hai : hai - 1;   // adj for next step
    }
    __syncthreads();
  }
}

// ---------------------------------------------------------------------------
extern "C" void kernel_launch(void* const* d_in, const int* in_sizes, int n_in,
                              void* d_out, int out_size, void* d_ws, size_t ws_size,
                              hipStream_t stream) {
  const float* inputs = (const float*)d_in[0];
  const int*   wids   = (const int*)d_in[1];
  const float* embed  = (const float*)d_in[2];
  const float* W      = (const float*)d_in[3];
  const float* Uw     = (const float*)d_in[4];
  const float* bias   = (const float*)d_in[5];
  const float* Wo     = (const float*)d_in[6];
  const float* bo     = (const float*)d_in[7];
  const int*   mlab   = (const int*)d_in[8];
  float* out = (float*)d_out;
  const int S = out_size / NBATCH;   // 192

  char* ws = (char*)d_ws;
  float* inpW = (float*)(ws + WS_INPW);
  float* embW = (float*)(ws + WS_EMBW);
  float* Uws  = (float*)(ws + WS_UWS);
  float* WotG = (float*)(ws + WS_WOT);

  prep_inpw<<<2048, 256, 0, stream>>>(inputs, W, inpW);
  prep_embw<<<48, 256, 0, stream>>>(embed, W, bias, embW);
  prep_uws<<<64, 256, 0, stream>>>(Uw, Uws);
  prep_wot<<<1, 256, 0, stream>>>(Wo, WotG);
  dec_main<<<64, 1024, 0, stream>>>(wids, bo, mlab, out, inpW, embW, Uws, WotG, S);
}